// Round 1
// baseline (821.681 us; speedup 1.0000x reference)
//
#include <hip/hip_runtime.h>
#include <cmath>

// FusedNetwork: Fourier encode (51ch) -> 64 -> 64 -> 64 -> 4 MLP, fp32.
// One thread per point. Both GEMV loops fully unrolled so enc[]/h[] stay in
// VGPRs (runtime-indexed arrays would spill to scratch). Weight/bias loads are
// wave-uniform -> expect s_load into SGPRs (scalar cache), inner loop pure
// v_fmac_f32 at ~157 TF vector roofline.

#define IN_CH 3
#define NFREQ 8
#define ENC   51   // 3 + 2*3*8
#define HID   64
#define OUTC  4

__global__ __launch_bounds__(256)
void fused_mlp_kernel(const float* __restrict__ x,
                      const float* __restrict__ W0, const float* __restrict__ b0,
                      const float* __restrict__ W1, const float* __restrict__ b1,
                      const float* __restrict__ W2, const float* __restrict__ b2,
                      const float* __restrict__ W3, const float* __restrict__ b3,
                      float* __restrict__ out, int n)
{
    const int i = blockIdx.x * blockDim.x + threadIdx.x;
    if (i >= n) return;

    const float c0 = x[3 * i + 0];
    const float c1 = x[3 * i + 1];
    const float c2 = x[3 * i + 2];

    // ----- Fourier encoding: [x, sin(x*f), cos(x*f)] ; freqs = 2^f * pi -----
    // Reference layout: enc[0:3]=x, enc[3+c*8+f]=sin, enc[27+c*8+f]=cos.
    float enc[ENC];
    enc[0] = c0; enc[1] = c1; enc[2] = c2;
    const float cs[3] = {c0, c1, c2};
    const float PI_F = 3.14159265358979323846f;  // rounds to fp32 pi, matches jnp
    #pragma unroll
    for (int ch = 0; ch < 3; ++ch) {
        #pragma unroll
        for (int f = 0; f < NFREQ; ++f) {
            const float freq = (float)(1 << f) * PI_F;  // exact 2^f scaling of fp32 pi
            const float xf = cs[ch] * freq;
            float s, co;
            sincosf(xf, &s, &co);
            enc[3  + ch * NFREQ + f] = s;
            enc[27 + ch * NFREQ + f] = co;
        }
    }

    // ----- layer 0: 51 -> 64, relu -----
    float h[HID];
    #pragma unroll
    for (int j = 0; j < HID; ++j) {
        float a = b0[j];
        #pragma unroll
        for (int k = 0; k < ENC; ++k)
            a = fmaf(W0[j * ENC + k], enc[k], a);
        h[j] = fmaxf(a, 0.0f);
    }

    // ----- layer 1: 64 -> 64, relu -----
    float g[HID];
    #pragma unroll
    for (int j = 0; j < HID; ++j) {
        float a = b1[j];
        #pragma unroll
        for (int k = 0; k < HID; ++k)
            a = fmaf(W1[j * HID + k], h[k], a);
        g[j] = fmaxf(a, 0.0f);
    }

    // ----- layer 2: 64 -> 64, relu (reuse h) -----
    #pragma unroll
    for (int j = 0; j < HID; ++j) {
        float a = b2[j];
        #pragma unroll
        for (int k = 0; k < HID; ++k)
            a = fmaf(W2[j * HID + k], g[k], a);
        h[j] = fmaxf(a, 0.0f);
    }

    // ----- layer 3: 64 -> 4 -----
    float o[OUTC];
    #pragma unroll
    for (int j = 0; j < OUTC; ++j) {
        float a = b3[j];
        #pragma unroll
        for (int k = 0; k < HID; ++k)
            a = fmaf(W3[j * HID + k], h[k], a);
        o[j] = a;
    }
    *reinterpret_cast<float4*>(out + 4 * (size_t)i) = make_float4(o[0], o[1], o[2], o[3]);
}

extern "C" void kernel_launch(void* const* d_in, const int* in_sizes, int n_in,
                              void* d_out, int out_size, void* d_ws, size_t ws_size,
                              hipStream_t stream)
{
    const float* x  = (const float*)d_in[0];
    const float* W0 = (const float*)d_in[1];
    const float* b0 = (const float*)d_in[2];
    const float* W1 = (const float*)d_in[3];
    const float* b1 = (const float*)d_in[4];
    const float* W2 = (const float*)d_in[5];
    const float* b2 = (const float*)d_in[6];
    const float* W3 = (const float*)d_in[7];
    const float* b3 = (const float*)d_in[8];
    float* out = (float*)d_out;

    const int n = in_sizes[0] / IN_CH;   // 1<<20
    const int block = 256;
    const int grid = (n + block - 1) / block;
    fused_mlp_kernel<<<grid, block, 0, stream>>>(x, W0, b0, W1, b1, W2, b2, W3, b3, out, n);
}

// Round 2
// 212.821 us; speedup vs baseline: 3.8609x; 3.8609x over previous
//
#include <hip/hip_runtime.h>
#include <cmath>

// Fused Fourier-MLP via split-f16 MFMA (v_mfma_f32_16x16x32_f16).
// x = hi + lo (f16 each); A*B ~= Ah*Bh + Ah*Bl + Al*Bh (lo*lo dropped, ~2^-22 rel).
// One wave = 64 points = 4 m-tiles of 16. Per-wave private LDS tile [64][64] f32
// holds enc / hidden activations between layers (C-layout -> A-layout transpose).
// XOR swizzle on 16B granules: float idx = row*64 + ((col>>2 ^ (row&15))<<2) + (col&3).
// No block barriers needed (same-wave DS ops are in-order).

typedef _Float16 half8 __attribute__((ext_vector_type(8)));
typedef float float4v __attribute__((ext_vector_type(4)));

#define PI_F 3.14159265358979323846f

// ---- one MLP layer: reads prev activations from hb, writes relu(out) back
//      (or final layer -> global). KIN = logical K (51 or 64), ROWS = out ch.
template <int KIN, int ROWS, bool RELU, bool LAST>
__device__ __forceinline__ void mlp_layer(const float* __restrict__ W,
                                          const float* __restrict__ bias,
                                          float* __restrict__ hb,
                                          float* __restrict__ outp,
                                          long long wbase, int lane, long long n)
{
    const int l15 = lane & 15;
    const int g   = lane >> 4;

    // ---- A-phase: pull all 4 m-tiles x 2 k-chunks into split-f16 fragments.
    // A-frag slot j of lane (group g) holds k = 32*c + 8*g + j  (row = point).
    half8 Ah[4][2], Al[4][2];
#pragma unroll
    for (int m = 0; m < 4; ++m) {
        const int row = 16 * m + l15;
#pragma unroll
        for (int c = 0; c < 2; ++c) {
            const int v0 = (8 * c + 2 * g) ^ l15;       // 16B-granule index (swizzled)
            const int v1 = (8 * c + 2 * g + 1) ^ l15;
            float4v r0 = *(const float4v*)&hb[row * 64 + v0 * 4];
            float4v r1 = *(const float4v*)&hb[row * 64 + v1 * 4];
#pragma unroll
            for (int j = 0; j < 4; ++j) {
                float v = r0[j];
                _Float16 hi = (_Float16)v;
                Ah[m][c][j] = hi;
                Al[m][c][j] = (_Float16)(v - (float)hi);
                float w = r1[j];
                _Float16 hw = (_Float16)w;
                Ah[m][c][4 + j] = hw;
                Al[m][c][4 + j] = (_Float16)(w - (float)hw);
            }
        }
    }

    constexpr int NT = (ROWS + 15) / 16;   // 4 for hidden, 1 for final
#pragma unroll
    for (int nt = 0; nt < NT; ++nt) {
        const int j = 16 * nt + l15;       // output channel (B column)
        const float bj = (j < ROWS) ? bias[j] : 0.f;

        // B-frag slot jj of lane (group g) holds W[j][k], k = 32*c + 8*g + jj.
        half8 Bh[2], Bl[2];
#pragma unroll
        for (int c = 0; c < 2; ++c) {
            if constexpr (KIN == 64 && ROWS == 64) {
                // aligned fast path: 2x float4 loads
                const float4v* Wv = (const float4v*)(W + j * 64 + 32 * c + 8 * g);
                float4v w0 = Wv[0], w1 = Wv[1];
#pragma unroll
                for (int jj = 0; jj < 4; ++jj) {
                    float w = w0[jj];
                    _Float16 hi = (_Float16)w;
                    Bh[c][jj] = hi; Bl[c][jj] = (_Float16)(w - (float)hi);
                    float w2 = w1[jj];
                    _Float16 h2 = (_Float16)w2;
                    Bh[c][4 + jj] = h2; Bl[c][4 + jj] = (_Float16)(w2 - (float)h2);
                }
            } else {
                // predicated scalar path (K=51 pad, or 4-row W3 pad)
#pragma unroll
                for (int jj = 0; jj < 8; ++jj) {
                    const int k = 32 * c + 8 * g + jj;
                    float w = (j < ROWS && k < KIN) ? W[j * KIN + k] : 0.f;
                    _Float16 hi = (_Float16)w;
                    Bh[c][jj] = hi; Bl[c][jj] = (_Float16)(w - (float)hi);
                }
            }
        }

#pragma unroll
        for (int m = 0; m < 4; ++m) {
            float4v acc = {bj, bj, bj, bj};   // bias as MFMA C-init
#pragma unroll
            for (int c = 0; c < 2; ++c) {
                acc = __builtin_amdgcn_mfma_f32_16x16x32_f16(Ah[m][c], Bh[c], acc, 0, 0, 0);
                acc = __builtin_amdgcn_mfma_f32_16x16x32_f16(Ah[m][c], Bl[c], acc, 0, 0, 0);
                acc = __builtin_amdgcn_mfma_f32_16x16x32_f16(Al[m][c], Bh[c], acc, 0, 0, 0);
            }
            // C-layout: col = l15 (channel j), rows = 16m + 4g + r (points)
            if constexpr (LAST) {
                if (l15 < 4) {
#pragma unroll
                    for (int r = 0; r < 4; ++r) {
                        long long p = wbase + 16 * m + 4 * g + r;
                        if (p < n) outp[p * 4 + l15] = acc[r];
                    }
                }
            } else {
#pragma unroll
                for (int r = 0; r < 4; ++r) {
                    float v = acc[r];
                    if (RELU) v = fmaxf(v, 0.f);
                    const int row = 16 * m + 4 * g + r;
                    const int col = 16 * nt + l15;
                    hb[row * 64 + ((((col >> 2) ^ (row & 15))) << 2) + (col & 3)] = v;
                }
            }
        }
    }
}

__global__ __launch_bounds__(256)
void fused_mlp_mfma(const float* __restrict__ x,
                    const float* __restrict__ W0, const float* __restrict__ b0,
                    const float* __restrict__ W1, const float* __restrict__ b1,
                    const float* __restrict__ W2, const float* __restrict__ b2,
                    const float* __restrict__ W3, const float* __restrict__ b3,
                    float* __restrict__ out, long long n)
{
    __shared__ float hbuf[4][64 * 64];    // 64 KB: per-wave private 16 KB tiles
    const int tid  = threadIdx.x;
    const int wave = tid >> 6;
    const int lane = tid & 63;
    const int l15  = lane & 15;
    float* hb = hbuf[wave];

    const long long wbase = (long long)blockIdx.x * 256 + wave * 64;

    // ---- encoding: lane computes point (wbase+lane)'s 64-ch encoding -> LDS row `lane`
    {
        long long p = wbase + lane;
        if (p > n - 1) p = n - 1;
        float xc[3] = {x[3 * p + 0], x[3 * p + 1], x[3 * p + 2]};
        float e[64];
        e[0] = xc[0]; e[1] = xc[1]; e[2] = xc[2];
#pragma unroll
        for (int ch = 0; ch < 3; ++ch) {
#pragma unroll
            for (int f = 0; f < 8; ++f) {
                float s, c;
                sincosf(xc[ch] * (PI_F * (float)(1 << f)), &s, &c);
                e[3 + ch * 8 + f]  = s;
                e[27 + ch * 8 + f] = c;
            }
        }
#pragma unroll
        for (int k = 51; k < 64; ++k) e[k] = 0.f;
#pragma unroll
        for (int cb = 0; cb < 16; ++cb) {
            float4v v = {e[4 * cb], e[4 * cb + 1], e[4 * cb + 2], e[4 * cb + 3]};
            *(float4v*)&hb[lane * 64 + ((cb ^ l15) << 2)] = v;   // row=lane, row&15=l15
        }
    }
    // no barrier needed: LDS tile is wave-private, DS ops are in-order per wave

    mlp_layer<51, 64, true,  false>(W0, b0, hb, nullptr, wbase, lane, n);
    mlp_layer<64, 64, true,  false>(W1, b1, hb, nullptr, wbase, lane, n);
    mlp_layer<64, 64, true,  false>(W2, b2, hb, nullptr, wbase, lane, n);
    mlp_layer<64, 4,  false, true >(W3, b3, hb, out,     wbase, lane, n);
}

extern "C" void kernel_launch(void* const* d_in, const int* in_sizes, int n_in,
                              void* d_out, int out_size, void* d_ws, size_t ws_size,
                              hipStream_t stream)
{
    const float* x  = (const float*)d_in[0];
    const float* W0 = (const float*)d_in[1];
    const float* b0 = (const float*)d_in[2];
    const float* W1 = (const float*)d_in[3];
    const float* b1 = (const float*)d_in[4];
    const float* W2 = (const float*)d_in[5];
    const float* b2 = (const float*)d_in[6];
    const float* W3 = (const float*)d_in[7];
    const float* b3 = (const float*)d_in[8];
    float* out = (float*)d_out;

    const long long n = in_sizes[0] / 3;           // 1<<20 points
    const int block = 256;                          // 4 waves, 64 points each
    const int grid = (int)((n + 255) / 256);
    fused_mlp_mfma<<<grid, block, 0, stream>>>(x, W0, b0, W1, b1, W2, b2, W3, b3, out, n);
}